// Round 1
// baseline (825.674 us; speedup 1.0000x reference)
//
#include <hip/hip_runtime.h>
#include <stdint.h>

#define DEV __device__ __forceinline__

typedef __attribute__((ext_vector_type(8))) short bh8;
typedef __attribute__((ext_vector_type(4))) float f4;

DEV unsigned short f2bf(float f) {
    union { float f; uint32_t u; } c; c.f = f;
    uint32_t u = c.u;
    uint32_t r = (u + 0x7fffu + ((u >> 16) & 1u)) >> 16;
    return (unsigned short)r;
}
DEV float bf2f(unsigned short h) {
    union { uint32_t u; float f; } c; c.u = ((uint32_t)h) << 16;
    return c.f;
}

// ---------------- fp32 -> bf16 convert (vectorized) ----------------
__global__ __launch_bounds__(256) void cvt_kernel(const float* __restrict__ in,
                                                  unsigned short* __restrict__ out, int n4) {
    int i = blockIdx.x * 256 + threadIdx.x;
    if (i >= n4) return;
    const float4 v = ((const float4*)in)[i];
    ushort4 o;
    o.x = f2bf(v.x); o.y = f2bf(v.y); o.z = f2bf(v.z); o.w = f2bf(v.w);
    ((ushort4*)out)[i] = o;
}

// ---------------- row_ptr from sorted dst (binary search) ----------------
__global__ __launch_bounds__(256) void rowptr_kernel(const int* __restrict__ dst,
                                                     int* __restrict__ rp, int n, int e) {
    int i = blockIdx.x * 256 + threadIdx.x;
    if (i > n) return;
    int lo = 0, hi = e;
    while (lo < hi) { int mid = (lo + hi) >> 1; if (dst[mid] < i) lo = mid + 1; else hi = mid; }
    rp[i] = lo;
}

// ---------------- segment-sum aggregation: one wave per node ----------------
// h: bf16 [N][256], m_out: bf16 [N][256]. lane owns 4 features (8B loads).
__global__ __launch_bounds__(256) void agg_kernel(const unsigned short* __restrict__ h,
                                                  const int* __restrict__ src,
                                                  const int* __restrict__ rp,
                                                  unsigned short* __restrict__ mout, int nNodes) {
    const int node = blockIdx.x * 4 + (threadIdx.x >> 6);
    if (node >= nNodes) return;
    const int lane = threadIdx.x & 63;
    const int beg = rp[node], end = rp[node + 1];
    float a0 = 0.f, a1 = 0.f, a2 = 0.f, a3 = 0.f;
    int e = beg;
    for (; e + 4 <= end; e += 4) {   // 4 independent gathers in flight (MLP)
        const int s0 = src[e], s1 = src[e+1], s2 = src[e+2], s3 = src[e+3];
        ushort4 v0 = *(const ushort4*)&h[(size_t)s0 * 256 + lane * 4];
        ushort4 v1 = *(const ushort4*)&h[(size_t)s1 * 256 + lane * 4];
        ushort4 v2 = *(const ushort4*)&h[(size_t)s2 * 256 + lane * 4];
        ushort4 v3 = *(const ushort4*)&h[(size_t)s3 * 256 + lane * 4];
        a0 += bf2f(v0.x) + bf2f(v1.x) + bf2f(v2.x) + bf2f(v3.x);
        a1 += bf2f(v0.y) + bf2f(v1.y) + bf2f(v2.y) + bf2f(v3.y);
        a2 += bf2f(v0.z) + bf2f(v1.z) + bf2f(v2.z) + bf2f(v3.z);
        a3 += bf2f(v0.w) + bf2f(v1.w) + bf2f(v2.w) + bf2f(v3.w);
    }
    for (; e < end; ++e) {
        const int s = src[e];
        ushort4 v = *(const ushort4*)&h[(size_t)s * 256 + lane * 4];
        a0 += bf2f(v.x); a1 += bf2f(v.y); a2 += bf2f(v.z); a3 += bf2f(v.w);
    }
    ushort4 o;
    o.x = f2bf(a0); o.y = f2bf(a1); o.z = f2bf(a2); o.w = f2bf(a3);
    *(ushort4*)&mout[(size_t)node * 256 + lane * 4] = o;
}

// ---------------- MFMA GEMM: out[M][256] = concat_seg(A_seg) @ concat(B_seg)^T + bias ----------------
// B is (out=256, in=256) row-major, i.e. exactly the B^T-input GEMM form.
// Tile: BM=64 rows x BN=256 cols (full row for l2norm). 4 waves, wave w -> cols [64w,64w+64).
// EPMODE: 0 = PRE (relu then l2norm), 1 = CONV (l2norm then relu), 2 = JK (relu only).
template <int NSEG, int EPMODE>
__global__ __launch_bounds__(256) void gemm_kernel(
    const unsigned short* __restrict__ A0, const unsigned short* __restrict__ A1,
    const unsigned short* __restrict__ B0, const unsigned short* __restrict__ B1,
    const float* __restrict__ bias, unsigned short* __restrict__ Out, int M) {
    __shared__ unsigned short Alds[64 * 32];    // 64 rows x 32 k, XOR-swizzled 16B slots
    __shared__ unsigned short Blds[256 * 32];   // 256 out-cols x 32 k, same swizzle
    __shared__ float ssq_lds[4][64];

    const int t = threadIdx.x;
    const int wave = t >> 6;
    const int lane = t & 63;
    const int l15 = lane & 15;
    const int kh = lane >> 4;          // k-chunk 0..3 (8 bf16 each)
    const int rowBase = blockIdx.x * 64;

    f4 acc[4][4];
#pragma unroll
    for (int m = 0; m < 4; m++)
#pragma unroll
        for (int n = 0; n < 4; n++) acc[m][n] = f4{0.f, 0.f, 0.f, 0.f};

    // staging: thread t covers row t>>2, 16B slot t&3
    const int sRow = t >> 2;
    const int sSlot = t & 3;
    int grA = rowBase + sRow; if (grA > M - 1) grA = M - 1;   // tail clamp (stores guarded)
    const size_t gA = (size_t)grA * 256 + sSlot * 8;
    const int aw = sRow * 32 + ((sSlot ^ ((sRow >> 1) & 3)) * 8);  // swizzled LDS offset

#pragma unroll
    for (int seg = 0; seg < NSEG; ++seg) {
        const unsigned short* Ap = (NSEG == 2 && seg == 1) ? A1 : A0;
        const unsigned short* Bp = (NSEG == 2 && seg == 1) ? B1 : B0;
        for (int k0 = 0; k0 < 256; k0 += 32) {
            __syncthreads();
            *(bh8*)&Alds[aw] = *(const bh8*)&Ap[gA + k0];
#pragma unroll
            for (int p = 0; p < 4; ++p) {
                const int rb = p * 64 + sRow;
                *(bh8*)&Blds[rb * 32 + ((sSlot ^ ((rb >> 1) & 3)) * 8)] =
                    *(const bh8*)&Bp[(size_t)rb * 256 + k0 + sSlot * 8];
            }
            __syncthreads();
            bh8 a[4], b[4];
#pragma unroll
            for (int m = 0; m < 4; m++) {
                const int ra = m * 16 + l15;
                a[m] = *(const bh8*)&Alds[ra * 32 + ((kh ^ ((ra >> 1) & 3)) * 8)];
            }
#pragma unroll
            for (int n = 0; n < 4; n++) {
                const int rb = wave * 64 + n * 16 + l15;
                b[n] = *(const bh8*)&Blds[rb * 32 + ((kh ^ ((rb >> 1) & 3)) * 8)];
            }
#pragma unroll
            for (int m = 0; m < 4; m++)
#pragma unroll
                for (int n = 0; n < 4; n++)
                    acc[m][n] = __builtin_amdgcn_mfma_f32_16x16x32_bf16(a[m], b[n], acc[m][n], 0, 0, 0);
        }
    }

    // ---- epilogue ----  C/D layout: col = lane&15, row = (lane>>4)*4 + reg  [m89-verified]
    const int cBase = wave * 64 + l15;
    float sq[4][4];
#pragma unroll
    for (int m = 0; m < 4; m++) { sq[m][0] = 0.f; sq[m][1] = 0.f; sq[m][2] = 0.f; sq[m][3] = 0.f; }
#pragma unroll
    for (int n = 0; n < 4; n++) {
        const float bv = bias[cBase + n * 16];
#pragma unroll
        for (int m = 0; m < 4; m++)
#pragma unroll
            for (int r = 0; r < 4; r++) {
                float v = acc[m][n][r] + bv;
                if (EPMODE != 1) v = fmaxf(v, 0.f);   // PRE/JK: relu before norm/store
                acc[m][n][r] = v;
                sq[m][r] += v * v;
            }
    }

    if (EPMODE != 2) {
        // reduce ssq across the 16 col-lanes of this wave
#pragma unroll
        for (int mask = 1; mask < 16; mask <<= 1)
#pragma unroll
            for (int m = 0; m < 4; m++)
#pragma unroll
                for (int r = 0; r < 4; r++) sq[m][r] += __shfl_xor(sq[m][r], mask);
        if (l15 == 0) {
#pragma unroll
            for (int m = 0; m < 4; m++)
#pragma unroll
                for (int r = 0; r < 4; r++) ssq_lds[wave][m * 16 + kh * 4 + r] = sq[m][r];
        }
        __syncthreads();
#pragma unroll
        for (int m = 0; m < 4; m++)
#pragma unroll
            for (int r = 0; r < 4; r++) {
                const int rr = m * 16 + kh * 4 + r;
                const float s = ssq_lds[0][rr] + ssq_lds[1][rr] + ssq_lds[2][rr] + ssq_lds[3][rr];
                sq[m][r] = 1.f / fmaxf(sqrtf(s), 1e-12f);
            }
    }

#pragma unroll
    for (int m = 0; m < 4; m++)
#pragma unroll
        for (int r = 0; r < 4; r++) {
            const int grow = rowBase + m * 16 + kh * 4 + r;
            if (grow < M) {
#pragma unroll
                for (int n = 0; n < 4; n++) {
                    float v = acc[m][n][r];
                    if (EPMODE != 2) v *= sq[m][r];
                    if (EPMODE == 1) v = fmaxf(v, 0.f);  // CONV: relu after norm
                    Out[(size_t)grow * 256 + cBase + n * 16] = f2bf(v);
                }
            }
        }
}

// ---------------- final: logits = t @ W_post^T + b_post, then log_softmax ----------------
// wave-per-row; W_post packed in LDS as [k/4][c][4] f32 for conflict-light b128 reads.
__global__ __launch_bounds__(256) void final_kernel(const unsigned short* __restrict__ T,
                                                    const float* __restrict__ Wp,
                                                    const float* __restrict__ bp,
                                                    float* __restrict__ out, int M) {
    __shared__ float Wl[64 * 192];   // 64 k-quads x 48 classes x 4 = 48 KB
    __shared__ float tl[4][256];
    for (int idx = threadIdx.x; idx < 47 * 256; idx += 256) {
        const int c = idx >> 8, k = idx & 255;
        Wl[(k >> 2) * 192 + c * 4 + (k & 3)] = Wp[idx];
    }
    __syncthreads();
    const int wave = threadIdx.x >> 6, lane = threadIdx.x & 63;
    const int c = (lane < 47) ? lane : 0;
    const float bias = bp[c];
    for (int row = blockIdx.x * 4 + wave; row < M; row += gridDim.x * 4) {
        ushort4 v = *(const ushort4*)&T[(size_t)row * 256 + lane * 4];
        float4 tv; tv.x = bf2f(v.x); tv.y = bf2f(v.y); tv.z = bf2f(v.z); tv.w = bf2f(v.w);
        *(float4*)&tl[wave][lane * 4] = tv;
        asm volatile("s_waitcnt lgkmcnt(0)" ::: "memory");
        __builtin_amdgcn_wave_barrier();
        float acc = bias;
#pragma unroll 8
        for (int k4 = 0; k4 < 64; ++k4) {
            const float4 w4 = *(const float4*)&Wl[k4 * 192 + c * 4];
            const float4 t4 = *(const float4*)&tl[wave][k4 * 4];
            acc += w4.x * t4.x + w4.y * t4.y + w4.z * t4.z + w4.w * t4.w;
        }
        float x = (lane < 47) ? acc : -3.0e38f;
        float mx = x;
#pragma unroll
        for (int msk = 1; msk < 64; msk <<= 1) mx = fmaxf(mx, __shfl_xor(mx, msk));
        float ex = (lane < 47) ? expf(x - mx) : 0.f;
        float se = ex;
#pragma unroll
        for (int msk = 1; msk < 64; msk <<= 1) se += __shfl_xor(se, msk);
        const float ls = logf(se);
        if (lane < 47) out[(size_t)row * 47 + lane] = x - mx - ls;
        asm volatile("s_waitcnt lgkmcnt(0)" ::: "memory");
        __builtin_amdgcn_wave_barrier();
    }
}

extern "C" void kernel_launch(void* const* d_in, const int* in_sizes, int n_in,
                              void* d_out, int out_size, void* d_ws, size_t ws_size,
                              hipStream_t stream) {
    const float* x      = (const float*)d_in[0];
    const int*   src    = (const int*)d_in[1];
    const int*   dst    = (const int*)d_in[2];
    const float* W_pre  = (const float*)d_in[3];
    const float* b_pre  = (const float*)d_in[4];
    const float* Wl1    = (const float*)d_in[5];
    const float* bl1    = (const float*)d_in[6];
    const float* Wr1    = (const float*)d_in[7];
    const float* Wl2    = (const float*)d_in[8];
    const float* bl2    = (const float*)d_in[9];
    const float* Wr2    = (const float*)d_in[10];
    const float* W_jk   = (const float*)d_in[11];
    const float* b_jk   = (const float*)d_in[12];
    const float* W_post = (const float*)d_in[13];
    const float* b_post = (const float*)d_in[14];

    const int N = in_sizes[0] / 256;
    const int E = in_sizes[1];

    char* ws = (char*)d_ws;
    const size_t HB = (size_t)N * 256 * 2;
    unsigned short* bufA = (unsigned short*)ws; ws += HB;   // xb -> h2 -> ...
    unsigned short* bufB = (unsigned short*)ws; ws += HB;   // h0 -> t
    unsigned short* bufC = (unsigned short*)ws; ws += HB;   // m1 -> m2
    unsigned short* bufD = (unsigned short*)ws; ws += HB;   // h1
    unsigned short* wb[6];
    for (int i = 0; i < 6; i++) { wb[i] = (unsigned short*)ws; ws += (size_t)256 * 256 * 2; }
    int* rp = (int*)ws; ws += (size_t)(N + 1) * 4;

    // converts: x and the six 256x256 weights to bf16
    const int nx4 = (N * 256) / 4;
    cvt_kernel<<<(nx4 + 255) / 256, 256, 0, stream>>>(x, bufA, nx4);
    const float* wsrc[6] = { W_pre, Wl1, Wr1, Wl2, Wr2, W_jk };
    for (int i = 0; i < 6; i++)
        cvt_kernel<<<64, 256, 0, stream>>>(wsrc[i], wb[i], 16384);
    rowptr_kernel<<<(N + 1 + 255) / 256, 256, 0, stream>>>(dst, rp, N, E);

    const int gB = (N + 63) / 64;
    // pre-MLP: h0 = l2norm(relu(x @ W_pre^T + b_pre))
    gemm_kernel<1, 0><<<gB, 256, 0, stream>>>(bufA, nullptr, wb[0], nullptr, b_pre, bufB, N);
    // conv1
    agg_kernel<<<(N + 3) / 4, 256, 0, stream>>>(bufB, src, rp, bufC, N);
    gemm_kernel<2, 1><<<gB, 256, 0, stream>>>(bufC, bufB, wb[1], wb[2], bl1, bufD, N);
    // conv2
    agg_kernel<<<(N + 3) / 4, 256, 0, stream>>>(bufD, src, rp, bufC, N);
    gemm_kernel<2, 1><<<gB, 256, 0, stream>>>(bufC, bufD, wb[3], wb[4], bl2, bufA, N);
    // jk: t = relu(h2 @ W_jk^T + b_jk)
    gemm_kernel<1, 2><<<gB, 256, 0, stream>>>(bufA, nullptr, wb[5], nullptr, b_jk, bufB, N);
    // post + log_softmax
    final_kernel<<<1024, 256, 0, stream>>>(bufB, W_post, b_post, (float*)d_out, N);
}